// Round 2
// baseline (3023.435 us; speedup 1.0000x reference)
//
#include <hip/hip_runtime.h>

#define NBPR 32  // GEMM blocks per relation

// ---------------- build node -> compact id map ----------------
__global__ void k_build_map(const int* __restrict__ tri_nodes, int* __restrict__ map,
                            int* __restrict__ uniq, int* __restrict__ counter, int n) {
  int i = blockIdx.x * blockDim.x + threadIdx.x;
  if (i >= n) return;
  int node = tri_nodes[i];
  int old = atomicCAS(&map[node], -1, -2);
  if (old == -1) {
    int mid = atomicAdd(counter, 1);
    uniq[mid] = node;
    map[node] = mid;
  }
}

// ---------------- count needed edges per (mid,rel) and per rel ----------------
__global__ void k_count(const int* __restrict__ edst, const int* __restrict__ erel,
                        const int* __restrict__ map, int* __restrict__ cnt_c,
                        int* __restrict__ bins, int E) {
  __shared__ int h[8];
  if (threadIdx.x < 8) h[threadIdx.x] = 0;
  __syncthreads();
  int stride = gridDim.x * blockDim.x;
  for (int i = blockIdx.x * blockDim.x + threadIdx.x; i < E; i += stride) {
    int mid = map[edst[i]];
    if (mid >= 0) {
      int r = erel[i];
      atomicAdd(&cnt_c[mid * 8 + r], 1);
      atomicAdd(&h[r], 1);
    }
  }
  __syncthreads();
  if (threadIdx.x < 8 && h[threadIdx.x]) atomicAdd(&bins[threadIdx.x], h[threadIdx.x]);
}

// ---------------- tiny prefix scan over 8 relation bins ----------------
__global__ void k_scan(const int* __restrict__ bins, int* __restrict__ bin_start,
                       int* __restrict__ bin_ofs) {
  if (threadIdx.x == 0) {
    int s = 0;
    for (int r = 0; r < 8; ++r) {
      bin_start[r] = s;
      bin_ofs[r] = s;
      s += bins[r];
    }
    bin_start[8] = s;
  }
}

// ---------------- scatter needed edges sorted by relation ----------------
__global__ void k_scatter(const int* __restrict__ esrc, const int* __restrict__ edst,
                          const int* __restrict__ erel, const int* __restrict__ map,
                          int* __restrict__ bin_ofs, int* __restrict__ s_src,
                          int* __restrict__ s_mid, int E) {
  int stride = gridDim.x * blockDim.x;
  int i0 = blockIdx.x * blockDim.x + threadIdx.x;
  int niter = (E + stride - 1) / stride;
  int lane = threadIdx.x & 63;
  for (int it = 0; it < niter; ++it) {
    int i = i0 + it * stride;
    bool valid = i < E;
    int mid = -1, r = -1, src = 0;
    if (valid) {
      mid = map[edst[i]];
      if (mid >= 0) { r = erel[i]; src = esrc[i]; }
    }
#pragma unroll
    for (int rr = 0; rr < 8; ++rr) {
      unsigned long long m = __ballot(r == rr);
      if (m == 0ull) continue;
      int leader = __ffsll(m) - 1;
      int base = 0;
      if (lane == leader) base = atomicAdd(&bin_ofs[rr], (int)__popcll(m));
      base = __shfl(base, leader);
      if (r == rr) {
        int pos = base + (int)__popcll(m & ((1ull << lane) - 1ull));
        s_src[pos] = src;
        s_mid[pos] = mid;
      }
    }
  }
}

// ---------------- per-relation tiled GEMM of scaled gathered X rows ----------------
// chunk = 128 edges, block = 256 threads, 8x8 micro-tile per thread.
__global__ __launch_bounds__(256) void k_agg(
    const float* __restrict__ X, const float* __restrict__ W_rel,
    const int* __restrict__ s_src, const int* __restrict__ s_mid,
    const int* __restrict__ cnt_c, const int* __restrict__ bin_start,
    float* __restrict__ Hacc) {
  __shared__ float w_lds[128 * 128];   // 64 KB
  __shared__ float x_lds[128 * 132];   // 67.6 KB (pad 132, XOR-swizzled float4s)
  __shared__ int mid_lds[128];

  int rel = blockIdx.x / NBPR;
  int blk = blockIdx.x % NBPR;
  int t = threadIdx.x;

  {  // stage W_rel[rel] (d-major, 128x128)
    const float4* w4 = (const float4*)(W_rel + rel * 16384);
    float4* wl4 = (float4*)w_lds;
#pragma unroll
    for (int i = 0; i < 16; ++i) wl4[t + i * 256] = w4[t + i * 256];
  }

  int e_begin = bin_start[rel];
  int e_end = bin_start[rel + 1];
  int nchunks = (e_end - e_begin + 127) >> 7;

  int ty = t >> 4;  // 0..15 -> edges ty*8 .. ty*8+7
  int tx = t & 15;  // j = tx*4 + (k&3) + 64*(k>>2)

  for (int c = blk; c < nchunks; c += NBPR) {
    int eb = e_begin + (c << 7);
    int n = min(128, e_end - eb);

    __syncthreads();  // previous compute done before overwriting x_lds

    {  // stage 128 norm-scaled X rows: thread t -> edge t>>1, half t&1
      int e = t >> 1, half = t & 1;
      float nrm = 0.f;
      const float4* xr = nullptr;
      int mid = -1;
      if (e < n) {
        int src = s_src[eb + e];
        mid = s_mid[eb + e];
        int cc = cnt_c[mid * 8 + rel];
        nrm = 1.0f / (float)(cc > 0 ? cc : 1);
        xr = (const float4*)(X + (long long)src * 128);
      }
      float4* xl4 = (float4*)(x_lds + e * 132);
      int key = (e >> 3) & 3;  // bank-spread swizzle key
#pragma unroll
      for (int q = 0; q < 16; ++q) {
        int d4 = half * 16 + q;
        float4 v;
        if (xr) {
          v = xr[d4];
          v.x *= nrm; v.y *= nrm; v.z *= nrm; v.w *= nrm;
        } else {
          v = make_float4(0.f, 0.f, 0.f, 0.f);
        }
        xl4[d4 ^ key] = v;
      }
      if (half == 0) mid_lds[e] = mid;
    }
    __syncthreads();

    float acc[8][8];
#pragma unroll
    for (int i = 0; i < 8; ++i)
#pragma unroll
      for (int k = 0; k < 8; ++k) acc[i][k] = 0.f;

    for (int d = 0; d < 128; d += 4) {
      int sw = d >> 2;
      float4 a[8];
#pragma unroll
      for (int i = 0; i < 8; ++i) {
        int e = ty * 8 + i;
        const float4* xe = (const float4*)(x_lds + e * 132);
        a[i] = xe[sw ^ (ty & 3)];  // FIX: write key was (e>>3)&3 == ty&3, not ty
      }
#pragma unroll
      for (int dd = 0; dd < 4; ++dd) {
        float4 b0 = *(const float4*)&w_lds[(d + dd) * 128 + tx * 4];
        float4 b1 = *(const float4*)&w_lds[(d + dd) * 128 + tx * 4 + 64];
        float bv[8] = {b0.x, b0.y, b0.z, b0.w, b1.x, b1.y, b1.z, b1.w};
#pragma unroll
        for (int i = 0; i < 8; ++i) {
          float av = ((const float*)&a[i])[dd];
#pragma unroll
          for (int k = 0; k < 8; ++k) acc[i][k] += av * bv[k];
        }
      }
    }

    // accumulate into compact Hacc
#pragma unroll
    for (int i = 0; i < 8; ++i) {
      int e = ty * 8 + i;
      int mid = mid_lds[e];
      if (mid >= 0) {
        float* outp = Hacc + (size_t)mid * 128 + tx * 4;
#pragma unroll
        for (int k = 0; k < 8; ++k)
          atomicAdd(outp + (k & 3) + 64 * (k >> 2), acc[i][k]);
      }
    }
  }
}

// ---------------- H = relu(Hacc + X @ W_self + b) for needed rows ----------------
__global__ __launch_bounds__(256) void k_final(
    const float* __restrict__ X, const float* __restrict__ W_self,
    const float* __restrict__ bvec, const int* __restrict__ uniq,
    const int* __restrict__ counter, float* __restrict__ Hacc) {
  __shared__ float w_lds[128 * 128];
  __shared__ float x_lds[256];
  int t = threadIdx.x;
  {
    const float4* w4 = (const float4*)W_self;
    float4* wl4 = (float4*)w_lds;
#pragma unroll
    for (int i = 0; i < 16; ++i) wl4[t + i * 256] = w4[t + i * 256];
  }
  int nm = *counter;
  int m = t >> 7, j = t & 127;
  float bj = bvec[j];
  for (int p = blockIdx.x; p * 2 < nm; p += gridDim.x) {
    int mid = p * 2 + m;
    __syncthreads();
    if (mid < nm) {
      int node = uniq[mid];
      x_lds[t] = X[(long long)node * 128 + j];
    }
    __syncthreads();
    if (mid < nm) {
      float acc = 0.f;
#pragma unroll 8
      for (int d = 0; d < 128; ++d) acc += x_lds[m * 128 + d] * w_lds[d * 128 + j];
      float v = acc + Hacc[(size_t)mid * 128 + j] + bj;
      Hacc[(size_t)mid * 128 + j] = v > 0.f ? v : 0.f;
    }
  }
}

// ---------------- DistMult score: one wave per triple ----------------
__global__ void k_score(const float* __restrict__ H, const int* __restrict__ map,
                        const float* __restrict__ rel_emb, const int* __restrict__ tri_nodes,
                        const int* __restrict__ tri_rel, float* __restrict__ out, int B) {
  int w = (blockIdx.x * blockDim.x + threadIdx.x) >> 6;
  int lane = threadIdx.x & 63;
  if (w >= B) return;
  int s = map[tri_nodes[w * 2]];
  int o = map[tri_nodes[w * 2 + 1]];
  const float* hs = H + (size_t)s * 128;
  const float* ho = H + (size_t)o * 128;
  const float* rr = rel_emb + (size_t)tri_rel[w] * 128;
  float p = hs[lane] * ho[lane] * rr[lane] + hs[lane + 64] * ho[lane + 64] * rr[lane + 64];
#pragma unroll
  for (int ofs = 32; ofs > 0; ofs >>= 1) p += __shfl_down(p, ofs);
  if (lane == 0) out[w] = p;
}

extern "C" void kernel_launch(void* const* d_in, const int* in_sizes, int n_in,
                              void* d_out, int out_size, void* d_ws, size_t ws_size,
                              hipStream_t stream) {
  const float* X       = (const float*)d_in[0];
  const float* W_rel   = (const float*)d_in[1];
  const float* W_self  = (const float*)d_in[2];
  const float* bvec    = (const float*)d_in[3];
  const float* rel_emb = (const float*)d_in[4];
  const int* edge_src  = (const int*)d_in[5];
  const int* edge_dst  = (const int*)d_in[6];
  const int* edge_rel  = (const int*)d_in[7];
  const int* tri_nodes = (const int*)d_in[8];
  const int* tri_rel   = (const int*)d_in[9];

  int N  = in_sizes[0] / 128;   // 100000
  int E  = in_sizes[5];         // 1600000
  int nt = in_sizes[8];         // 2*B = 32768 (max distinct needed nodes)
  int B  = in_sizes[9];         // 16384

  char* ws = (char*)d_ws;
  int* map       = (int*)ws;                       // N ints
  int* counter   = (int*)(ws + (size_t)N * 4);     // 1
  int* bins      = counter + 1;                    // 8
  int* bin_start = counter + 16;                   // 9
  int* bin_ofs   = counter + 32;                   // 8
  int* uniq      = counter + 64;                   // nt ints
  int* cnt_c     = uniq + nt;                      // nt*8 ints
  float* Hacc    = (float*)(cnt_c + (size_t)nt * 8);  // nt*128 floats
  int* s_src     = (int*)(Hacc + (size_t)nt * 128);   // E ints
  int* s_mid     = s_src + E;                         // E ints
  // total ws use: ~30 MB

  hipMemsetAsync(map, 0xFF, (size_t)N * 4, stream);                 // -1
  hipMemsetAsync(counter, 0, 64 * 4, stream);                       // counter+bins
  hipMemsetAsync(cnt_c, 0, (size_t)nt * 8 * 4, stream);
  hipMemsetAsync(Hacc, 0, (size_t)nt * 128 * 4, stream);

  k_build_map<<<(nt + 255) / 256, 256, 0, stream>>>(tri_nodes, map, uniq, counter, nt);
  k_count<<<1024, 256, 0, stream>>>(edge_dst, edge_rel, map, cnt_c, bins, E);
  k_scan<<<1, 64, 0, stream>>>(bins, bin_start, bin_ofs);
  k_scatter<<<1024, 256, 0, stream>>>(edge_src, edge_dst, edge_rel, map, bin_ofs,
                                      s_src, s_mid, E);
  k_agg<<<8 * NBPR, 256, 0, stream>>>(X, W_rel, s_src, s_mid, cnt_c, bin_start, Hacc);
  k_final<<<256, 256, 0, stream>>>(X, W_self, bvec, uniq, counter, Hacc);
  k_score<<<(B * 64 + 255) / 256, 256, 0, stream>>>(Hacc, map, rel_emb, tri_nodes,
                                                    tri_rel, (float*)d_out, B);
}

// Round 3
// 992.600 us; speedup vs baseline: 3.0460x; 3.0460x over previous
//
#include <hip/hip_runtime.h>

#define NBPR 32    // GEMM blocks per relation
#define SCHUNK 2048  // edges per scatter block (8 per thread)

// ---------------- build node -> compact id map ----------------
__global__ void k_build_map(const int* __restrict__ tri_nodes, int* __restrict__ map,
                            int* __restrict__ uniq, int* __restrict__ counter, int n) {
  int i = blockIdx.x * blockDim.x + threadIdx.x;
  if (i >= n) return;
  int node = tri_nodes[i];
  int old = atomicCAS(&map[node], -1, -2);
  if (old == -1) {
    int mid = atomicAdd(counter, 1);
    uniq[mid] = node;
    map[node] = mid;
  }
}

// ---------------- count needed edges per (mid,rel) and per rel ----------------
__global__ void k_count(const int* __restrict__ edst, const int* __restrict__ erel,
                        const int* __restrict__ map, int* __restrict__ cnt_c,
                        int* __restrict__ bins, int E) {
  __shared__ int h[8];
  if (threadIdx.x < 8) h[threadIdx.x] = 0;
  __syncthreads();
  int stride = gridDim.x * blockDim.x;
  for (int i = blockIdx.x * blockDim.x + threadIdx.x; i < E; i += stride) {
    int mid = map[edst[i]];
    if (mid >= 0) {
      int r = erel[i];
      atomicAdd(&cnt_c[mid * 8 + r], 1);
      atomicAdd(&h[r], 1);
    }
  }
  __syncthreads();
  if (threadIdx.x < 8 && h[threadIdx.x]) atomicAdd(&bins[threadIdx.x], h[threadIdx.x]);
}

// ---------------- tiny prefix scan over 8 relation bins ----------------
__global__ void k_scan(const int* __restrict__ bins, int* __restrict__ bin_start,
                       int* __restrict__ bin_ofs) {
  if (threadIdx.x == 0) {
    int s = 0;
    for (int r = 0; r < 8; ++r) {
      bin_start[r] = s;
      bin_ofs[r] = s;
      s += bins[r];
    }
    bin_start[8] = s;
  }
}

// ---------------- scatter needed edges sorted by relation ----------------
// Counting-sort structure: per-block LDS histogram, ONE global atomic per
// (block, relation) to reserve a range, LDS-atomic local ranks. No contended
// global round-trips (round-2 k_scatter burned 2040us on 8 hot addresses).
__global__ __launch_bounds__(256) void k_scatter(
    const int* __restrict__ esrc, const int* __restrict__ edst,
    const int* __restrict__ erel, const int* __restrict__ map,
    int* __restrict__ bin_ofs, int* __restrict__ s_src,
    int* __restrict__ s_mid, int E) {
  __shared__ int lcnt[8];
  __shared__ int lbase[8];
  int t = threadIdx.x;
  if (t < 8) lcnt[t] = 0;
  __syncthreads();

  int base = blockIdx.x * SCHUNK;
  int mid[8], r[8], src[8];
#pragma unroll
  for (int q = 0; q < 8; ++q) {
    int i = base + q * 256 + t;
    mid[q] = -1; r[q] = 0; src[q] = 0;
    if (i < E) {
      int m = map[edst[i]];
      if (m >= 0) { mid[q] = m; r[q] = erel[i]; src[q] = esrc[i]; }
    }
  }
#pragma unroll
  for (int q = 0; q < 8; ++q)
    if (mid[q] >= 0) atomicAdd(&lcnt[r[q]], 1);
  __syncthreads();
  if (t < 8) {
    int c = lcnt[t];
    lbase[t] = c ? atomicAdd(&bin_ofs[t], c) : 0;
    lcnt[t] = 0;
  }
  __syncthreads();
#pragma unroll
  for (int q = 0; q < 8; ++q) {
    if (mid[q] >= 0) {
      int rank = atomicAdd(&lcnt[r[q]], 1);
      int pos = lbase[r[q]] + rank;
      s_src[pos] = src[q];
      s_mid[pos] = mid[q];
    }
  }
}

// ---------------- per-relation tiled GEMM of scaled gathered X rows ----------------
// chunk = 128 edges, block = 256 threads, 8x8 micro-tile per thread.
__global__ __launch_bounds__(256) void k_agg(
    const float* __restrict__ X, const float* __restrict__ W_rel,
    const int* __restrict__ s_src, const int* __restrict__ s_mid,
    const int* __restrict__ cnt_c, const int* __restrict__ bin_start,
    float* __restrict__ Hacc) {
  __shared__ float w_lds[128 * 128];   // 64 KB
  __shared__ float x_lds[128 * 132];   // 67.6 KB (pad 132, XOR-swizzled float4s)
  __shared__ int mid_lds[128];

  int rel = blockIdx.x / NBPR;
  int blk = blockIdx.x % NBPR;
  int t = threadIdx.x;

  {  // stage W_rel[rel] (d-major, 128x128)
    const float4* w4 = (const float4*)(W_rel + rel * 16384);
    float4* wl4 = (float4*)w_lds;
#pragma unroll
    for (int i = 0; i < 16; ++i) wl4[t + i * 256] = w4[t + i * 256];
  }

  int e_begin = bin_start[rel];
  int e_end = bin_start[rel + 1];
  int nchunks = (e_end - e_begin + 127) >> 7;

  int ty = t >> 4;  // 0..15 -> edges ty*8 .. ty*8+7
  int tx = t & 15;  // j = tx*4 + (k&3) + 64*(k>>2)

  for (int c = blk; c < nchunks; c += NBPR) {
    int eb = e_begin + (c << 7);
    int n = min(128, e_end - eb);

    __syncthreads();  // previous compute done before overwriting x_lds

    {  // stage 128 norm-scaled X rows: thread t -> edge t>>1, half t&1
      int e = t >> 1, half = t & 1;
      float nrm = 0.f;
      const float4* xr = nullptr;
      int mid = -1;
      if (e < n) {
        int src = s_src[eb + e];
        mid = s_mid[eb + e];
        int cc = cnt_c[mid * 8 + rel];
        nrm = 1.0f / (float)(cc > 0 ? cc : 1);
        xr = (const float4*)(X + (long long)src * 128);
      }
      float4* xl4 = (float4*)(x_lds + e * 132);
      int key = (e >> 3) & 3;  // bank-spread swizzle key
#pragma unroll
      for (int q = 0; q < 16; ++q) {
        int d4 = half * 16 + q;
        float4 v;
        if (xr) {
          v = xr[d4];
          v.x *= nrm; v.y *= nrm; v.z *= nrm; v.w *= nrm;
        } else {
          v = make_float4(0.f, 0.f, 0.f, 0.f);
        }
        xl4[d4 ^ key] = v;
      }
      if (half == 0) mid_lds[e] = mid;
    }
    __syncthreads();

    float acc[8][8];
#pragma unroll
    for (int i = 0; i < 8; ++i)
#pragma unroll
      for (int k = 0; k < 8; ++k) acc[i][k] = 0.f;

    for (int d = 0; d < 128; d += 4) {
      int sw = d >> 2;
      float4 a[8];
#pragma unroll
      for (int i = 0; i < 8; ++i) {
        int e = ty * 8 + i;
        const float4* xe = (const float4*)(x_lds + e * 132);
        a[i] = xe[sw ^ (ty & 3)];  // matches write key (e>>3)&3
      }
#pragma unroll
      for (int dd = 0; dd < 4; ++dd) {
        float4 b0 = *(const float4*)&w_lds[(d + dd) * 128 + tx * 4];
        float4 b1 = *(const float4*)&w_lds[(d + dd) * 128 + tx * 4 + 64];
        float bv[8] = {b0.x, b0.y, b0.z, b0.w, b1.x, b1.y, b1.z, b1.w};
#pragma unroll
        for (int i = 0; i < 8; ++i) {
          float av = ((const float*)&a[i])[dd];
#pragma unroll
          for (int k = 0; k < 8; ++k) acc[i][k] += av * bv[k];
        }
      }
    }

    // accumulate into compact Hacc
#pragma unroll
    for (int i = 0; i < 8; ++i) {
      int e = ty * 8 + i;
      int mid = mid_lds[e];
      if (mid >= 0) {
        float* outp = Hacc + (size_t)mid * 128 + tx * 4;
#pragma unroll
        for (int k = 0; k < 8; ++k)
          atomicAdd(outp + (k & 3) + 64 * (k >> 2), acc[i][k]);
      }
    }
  }
}

// ---------------- H = relu(Hacc + X @ W_self + b) for needed rows ----------------
__global__ __launch_bounds__(256) void k_final(
    const float* __restrict__ X, const float* __restrict__ W_self,
    const float* __restrict__ bvec, const int* __restrict__ uniq,
    const int* __restrict__ counter, float* __restrict__ Hacc) {
  __shared__ float w_lds[128 * 128];
  __shared__ float x_lds[256];
  int t = threadIdx.x;
  {
    const float4* w4 = (const float4*)W_self;
    float4* wl4 = (float4*)w_lds;
#pragma unroll
    for (int i = 0; i < 16; ++i) wl4[t + i * 256] = w4[t + i * 256];
  }
  int nm = *counter;
  int m = t >> 7, j = t & 127;
  float bj = bvec[j];
  for (int p = blockIdx.x; p * 2 < nm; p += gridDim.x) {
    int mid = p * 2 + m;
    __syncthreads();
    if (mid < nm) {
      int node = uniq[mid];
      x_lds[t] = X[(long long)node * 128 + j];
    }
    __syncthreads();
    if (mid < nm) {
      float acc = 0.f;
#pragma unroll 8
      for (int d = 0; d < 128; ++d) acc += x_lds[m * 128 + d] * w_lds[d * 128 + j];
      float v = acc + Hacc[(size_t)mid * 128 + j] + bj;
      Hacc[(size_t)mid * 128 + j] = v > 0.f ? v : 0.f;
    }
  }
}

// ---------------- DistMult score: one wave per triple ----------------
__global__ void k_score(const float* __restrict__ H, const int* __restrict__ map,
                        const float* __restrict__ rel_emb, const int* __restrict__ tri_nodes,
                        const int* __restrict__ tri_rel, float* __restrict__ out, int B) {
  int w = (blockIdx.x * blockDim.x + threadIdx.x) >> 6;
  int lane = threadIdx.x & 63;
  if (w >= B) return;
  int s = map[tri_nodes[w * 2]];
  int o = map[tri_nodes[w * 2 + 1]];
  const float* hs = H + (size_t)s * 128;
  const float* ho = H + (size_t)o * 128;
  const float* rr = rel_emb + (size_t)tri_rel[w] * 128;
  float p = hs[lane] * ho[lane] * rr[lane] + hs[lane + 64] * ho[lane + 64] * rr[lane + 64];
#pragma unroll
  for (int ofs = 32; ofs > 0; ofs >>= 1) p += __shfl_down(p, ofs);
  if (lane == 0) out[w] = p;
}

extern "C" void kernel_launch(void* const* d_in, const int* in_sizes, int n_in,
                              void* d_out, int out_size, void* d_ws, size_t ws_size,
                              hipStream_t stream) {
  const float* X       = (const float*)d_in[0];
  const float* W_rel   = (const float*)d_in[1];
  const float* W_self  = (const float*)d_in[2];
  const float* bvec    = (const float*)d_in[3];
  const float* rel_emb = (const float*)d_in[4];
  const int* edge_src  = (const int*)d_in[5];
  const int* edge_dst  = (const int*)d_in[6];
  const int* edge_rel  = (const int*)d_in[7];
  const int* tri_nodes = (const int*)d_in[8];
  const int* tri_rel   = (const int*)d_in[9];

  int N  = in_sizes[0] / 128;   // 100000
  int E  = in_sizes[5];         // 1600000
  int nt = in_sizes[8];         // 2*B = 32768 (max distinct needed nodes)
  int B  = in_sizes[9];         // 16384

  char* ws = (char*)d_ws;
  int* map       = (int*)ws;                       // N ints
  int* counter   = (int*)(ws + (size_t)N * 4);     // 1
  int* bins      = counter + 1;                    // 8
  int* bin_start = counter + 16;                   // 9
  int* bin_ofs   = counter + 32;                   // 8
  int* uniq      = counter + 64;                   // nt ints
  int* cnt_c     = uniq + nt;                      // nt*8 ints
  float* Hacc    = (float*)(cnt_c + (size_t)nt * 8);  // nt*128 floats
  int* s_src     = (int*)(Hacc + (size_t)nt * 128);   // E ints
  int* s_mid     = s_src + E;                         // E ints
  // total ws use: ~30 MB

  hipMemsetAsync(map, 0xFF, (size_t)N * 4, stream);                 // -1
  hipMemsetAsync(counter, 0, 64 * 4, stream);                       // counter+bins
  hipMemsetAsync(cnt_c, 0, (size_t)nt * 8 * 4, stream);
  hipMemsetAsync(Hacc, 0, (size_t)nt * 128 * 4, stream);

  k_build_map<<<(nt + 255) / 256, 256, 0, stream>>>(tri_nodes, map, uniq, counter, nt);
  k_count<<<1024, 256, 0, stream>>>(edge_dst, edge_rel, map, cnt_c, bins, E);
  k_scan<<<1, 64, 0, stream>>>(bins, bin_start, bin_ofs);
  k_scatter<<<(E + SCHUNK - 1) / SCHUNK, 256, 0, stream>>>(edge_src, edge_dst, edge_rel,
                                                           map, bin_ofs, s_src, s_mid, E);
  k_agg<<<8 * NBPR, 256, 0, stream>>>(X, W_rel, s_src, s_mid, cnt_c, bin_start, Hacc);
  k_final<<<256, 256, 0, stream>>>(X, W_self, bvec, uniq, counter, Hacc);
  k_score<<<(B * 64 + 255) / 256, 256, 0, stream>>>(Hacc, map, rel_emb, tri_nodes,
                                                    tri_rel, (float*)d_out, B);
}

// Round 4
// 919.224 us; speedup vs baseline: 3.2891x; 1.0798x over previous
//
#include <hip/hip_runtime.h>

#define NBPR 32      // GEMM blocks per relation
#define SCHUNK 2048  // edges per scatter block (8 per thread)

// ---------------- build node -> compact id map ----------------
__global__ void k_build_map(const int* __restrict__ tri_nodes, int* __restrict__ map,
                            int* __restrict__ uniq, int* __restrict__ counter, int n) {
  int i = blockIdx.x * blockDim.x + threadIdx.x;
  if (i >= n) return;
  int node = tri_nodes[i];
  int old = atomicCAS(&map[node], -1, -2);
  if (old == -1) {
    int mid = atomicAdd(counter, 1);
    uniq[mid] = node;
    map[node] = mid;
  }
}

// ---------------- count needed edges per (mid,rel) and per rel ----------------
__global__ void k_count(const int* __restrict__ edst, const int* __restrict__ erel,
                        const int* __restrict__ map, int* __restrict__ cnt_c,
                        int* __restrict__ bins, int E) {
  __shared__ int h[8];
  if (threadIdx.x < 8) h[threadIdx.x] = 0;
  __syncthreads();
  int stride = gridDim.x * blockDim.x;
  for (int i = blockIdx.x * blockDim.x + threadIdx.x; i < E; i += stride) {
    int mid = map[edst[i]];
    if (mid >= 0) {
      int r = erel[i];
      atomicAdd(&cnt_c[mid * 8 + r], 1);
      atomicAdd(&h[r], 1);
    }
  }
  __syncthreads();
  if (threadIdx.x < 8 && h[threadIdx.x]) atomicAdd(&bins[threadIdx.x], h[threadIdx.x]);
}

// ---------------- tiny prefix scan over 8 relation bins ----------------
__global__ void k_scan(const int* __restrict__ bins, int* __restrict__ bin_start,
                       int* __restrict__ bin_ofs) {
  if (threadIdx.x == 0) {
    int s = 0;
    for (int r = 0; r < 8; ++r) {
      bin_start[r] = s;
      bin_ofs[r] = s;
      s += bins[r];
    }
    bin_start[8] = s;
  }
}

// ---------------- scatter needed edges sorted by relation ----------------
__global__ __launch_bounds__(256) void k_scatter(
    const int* __restrict__ esrc, const int* __restrict__ edst,
    const int* __restrict__ erel, const int* __restrict__ map,
    int* __restrict__ bin_ofs, int* __restrict__ s_src,
    int* __restrict__ s_mid, int E) {
  __shared__ int lcnt[8];
  __shared__ int lbase[8];
  int t = threadIdx.x;
  if (t < 8) lcnt[t] = 0;
  __syncthreads();

  int base = blockIdx.x * SCHUNK;
  int mid[8], r[8], src[8];
#pragma unroll
  for (int q = 0; q < 8; ++q) {
    int i = base + q * 256 + t;
    mid[q] = -1; r[q] = 0; src[q] = 0;
    if (i < E) {
      int m = map[edst[i]];
      if (m >= 0) { mid[q] = m; r[q] = erel[i]; src[q] = esrc[i]; }
    }
  }
#pragma unroll
  for (int q = 0; q < 8; ++q)
    if (mid[q] >= 0) atomicAdd(&lcnt[r[q]], 1);
  __syncthreads();
  if (t < 8) {
    int c = lcnt[t];
    lbase[t] = c ? atomicAdd(&bin_ofs[t], c) : 0;
    lcnt[t] = 0;
  }
  __syncthreads();
#pragma unroll
  for (int q = 0; q < 8; ++q) {
    if (mid[q] >= 0) {
      int rank = atomicAdd(&lcnt[r[q]], 1);
      int pos = lbase[r[q]] + rank;
      s_src[pos] = src[q];
      s_mid[pos] = mid[q];
    }
  }
}

// ---------------- per-relation tiled GEMM of scaled gathered X rows ----------------
// chunk = 128 edges, block = 512 threads (8 waves/CU vs round-3's 4),
// micro-tile = 8 edges x 4 cols per thread.
__global__ __launch_bounds__(512) void k_agg(
    const float* __restrict__ X, const float* __restrict__ W_rel,
    const int* __restrict__ s_src, const int* __restrict__ s_mid,
    const int* __restrict__ cnt_c, const int* __restrict__ bin_start,
    float* __restrict__ Hacc) {
  __shared__ float w_lds[128 * 128];   // 64 KB
  __shared__ float x_lds[128 * 132];   // 67.6 KB (pad 132, XOR-swizzled float4s)
  __shared__ int mid_lds[128];

  int rel = blockIdx.x / NBPR;
  int blk = blockIdx.x % NBPR;
  int t = threadIdx.x;

  {  // stage W_rel[rel] (d-major, 128x128): 4096 float4 / 512 threads
    const float4* w4 = (const float4*)(W_rel + rel * 16384);
    float4* wl4 = (float4*)w_lds;
#pragma unroll
    for (int i = 0; i < 8; ++i) wl4[t + i * 512] = w4[t + i * 512];
  }

  int e_begin = bin_start[rel];
  int e_end = bin_start[rel + 1];
  int nchunks = (e_end - e_begin + 127) >> 7;

  int ty = t >> 5;  // 0..15 -> edges ty*8 .. ty*8+7
  int tx = t & 31;  // cols tx*4 .. tx*4+3

  for (int c = blk; c < nchunks; c += NBPR) {
    int eb = e_begin + (c << 7);
    int n = min(128, e_end - eb);

    __syncthreads();  // previous compute done before overwriting x_lds

    {  // stage 128 norm-scaled X rows: thread t -> edge t>>2, quarter t&3
      int e = t >> 2, qtr = t & 3;
      float nrm = 0.f;
      const float4* xr = nullptr;
      int mid = -1;
      if (e < n) {
        int src = s_src[eb + e];
        mid = s_mid[eb + e];
        int cc = cnt_c[mid * 8 + rel];
        nrm = 1.0f / (float)(cc > 0 ? cc : 1);
        xr = (const float4*)(X + (long long)src * 128);
      }
      float4* xl4 = (float4*)(x_lds + e * 132);
      int key = (e >> 3) & 3;  // bank-spread swizzle key
#pragma unroll
      for (int q = 0; q < 8; ++q) {
        int d4 = qtr * 8 + q;
        float4 v;
        if (xr) {
          v = xr[d4];
          v.x *= nrm; v.y *= nrm; v.z *= nrm; v.w *= nrm;
        } else {
          v = make_float4(0.f, 0.f, 0.f, 0.f);
        }
        xl4[d4 ^ key] = v;
      }
      if (qtr == 0) mid_lds[e] = mid;
    }
    __syncthreads();

    float4 acc[8];
#pragma unroll
    for (int i = 0; i < 8; ++i) acc[i] = make_float4(0.f, 0.f, 0.f, 0.f);

    for (int d = 0; d < 128; d += 4) {
      int sw = d >> 2;
      float4 a[8];
#pragma unroll
      for (int i = 0; i < 8; ++i) {
        int e = ty * 8 + i;
        a[i] = ((const float4*)(x_lds + e * 132))[sw ^ (ty & 3)];  // key=(e>>3)&3==ty&3
      }
#pragma unroll
      for (int dd = 0; dd < 4; ++dd) {
        float4 b = *(const float4*)&w_lds[(d + dd) * 128 + tx * 4];
#pragma unroll
        for (int i = 0; i < 8; ++i) {
          float av = (dd == 0) ? a[i].x : (dd == 1) ? a[i].y : (dd == 2) ? a[i].z : a[i].w;
          acc[i].x += av * b.x;
          acc[i].y += av * b.y;
          acc[i].z += av * b.z;
          acc[i].w += av * b.w;
        }
      }
    }

    // accumulate into compact Hacc
#pragma unroll
    for (int i = 0; i < 8; ++i) {
      int mid = mid_lds[ty * 8 + i];
      if (mid >= 0) {
        float* outp = Hacc + (size_t)mid * 128 + tx * 4;
        atomicAdd(outp + 0, acc[i].x);
        atomicAdd(outp + 1, acc[i].y);
        atomicAdd(outp + 2, acc[i].z);
        atomicAdd(outp + 3, acc[i].w);
      }
    }
  }
}

// ---------------- H = relu(Hacc + X @ W_self + b) for needed rows ----------------
__global__ __launch_bounds__(512) void k_final(
    const float* __restrict__ X, const float* __restrict__ W_self,
    const float* __restrict__ bvec, const int* __restrict__ uniq,
    const int* __restrict__ counter, float* __restrict__ Hacc) {
  __shared__ float w_lds[128 * 128];
  __shared__ float x_lds[512];
  int t = threadIdx.x;
  {
    const float4* w4 = (const float4*)W_self;
    float4* wl4 = (float4*)w_lds;
#pragma unroll
    for (int i = 0; i < 8; ++i) wl4[t + i * 512] = w4[t + i * 512];
  }
  int nm = *counter;
  int m = t >> 7, j = t & 127;  // 4 rows per block-iteration
  float bj = bvec[j];
  for (int p = blockIdx.x; p * 4 < nm; p += gridDim.x) {
    int mid = p * 4 + m;
    __syncthreads();
    if (mid < nm) {
      int node = uniq[mid];
      x_lds[t] = X[(long long)node * 128 + j];
    }
    __syncthreads();
    if (mid < nm) {
      float acc = 0.f;
#pragma unroll 8
      for (int d = 0; d < 128; ++d) acc += x_lds[m * 128 + d] * w_lds[d * 128 + j];
      float v = acc + Hacc[(size_t)mid * 128 + j] + bj;
      Hacc[(size_t)mid * 128 + j] = v > 0.f ? v : 0.f;
    }
  }
}

// ---------------- DistMult score: one wave per triple ----------------
__global__ void k_score(const float* __restrict__ H, const int* __restrict__ map,
                        const float* __restrict__ rel_emb, const int* __restrict__ tri_nodes,
                        const int* __restrict__ tri_rel, float* __restrict__ out, int B) {
  int w = (blockIdx.x * blockDim.x + threadIdx.x) >> 6;
  int lane = threadIdx.x & 63;
  if (w >= B) return;
  int s = map[tri_nodes[w * 2]];
  int o = map[tri_nodes[w * 2 + 1]];
  const float* hs = H + (size_t)s * 128;
  const float* ho = H + (size_t)o * 128;
  const float* rr = rel_emb + (size_t)tri_rel[w] * 128;
  float p = hs[lane] * ho[lane] * rr[lane] + hs[lane + 64] * ho[lane + 64] * rr[lane + 64];
#pragma unroll
  for (int ofs = 32; ofs > 0; ofs >>= 1) p += __shfl_down(p, ofs);
  if (lane == 0) out[w] = p;
}

extern "C" void kernel_launch(void* const* d_in, const int* in_sizes, int n_in,
                              void* d_out, int out_size, void* d_ws, size_t ws_size,
                              hipStream_t stream) {
  const float* X       = (const float*)d_in[0];
  const float* W_rel   = (const float*)d_in[1];
  const float* W_self  = (const float*)d_in[2];
  const float* bvec    = (const float*)d_in[3];
  const float* rel_emb = (const float*)d_in[4];
  const int* edge_src  = (const int*)d_in[5];
  const int* edge_dst  = (const int*)d_in[6];
  const int* edge_rel  = (const int*)d_in[7];
  const int* tri_nodes = (const int*)d_in[8];
  const int* tri_rel   = (const int*)d_in[9];

  int N  = in_sizes[0] / 128;   // 100000
  int E  = in_sizes[5];         // 1600000
  int nt = in_sizes[8];         // 2*B = 32768 (max distinct needed nodes)
  int B  = in_sizes[9];         // 16384

  char* ws = (char*)d_ws;
  int* map       = (int*)ws;                       // N ints
  int* counter   = (int*)(ws + (size_t)N * 4);     // 1
  int* bins      = counter + 1;                    // 8
  int* bin_start = counter + 16;                   // 9
  int* bin_ofs   = counter + 32;                   // 8
  int* uniq      = counter + 64;                   // nt ints
  int* cnt_c     = uniq + nt;                      // nt*8 ints
  float* Hacc    = (float*)(cnt_c + (size_t)nt * 8);  // nt*128 floats
  int* s_src     = (int*)(Hacc + (size_t)nt * 128);   // E ints
  int* s_mid     = s_src + E;                         // E ints
  // total ws use: ~30 MB

  hipMemsetAsync(map, 0xFF, (size_t)N * 4, stream);                 // -1
  hipMemsetAsync(counter, 0, 64 * 4, stream);                       // counter+bins
  hipMemsetAsync(cnt_c, 0, (size_t)nt * 8 * 4, stream);
  hipMemsetAsync(Hacc, 0, (size_t)nt * 128 * 4, stream);

  k_build_map<<<(nt + 255) / 256, 256, 0, stream>>>(tri_nodes, map, uniq, counter, nt);
  k_count<<<1024, 256, 0, stream>>>(edge_dst, edge_rel, map, cnt_c, bins, E);
  k_scan<<<1, 64, 0, stream>>>(bins, bin_start, bin_ofs);
  k_scatter<<<(E + SCHUNK - 1) / SCHUNK, 256, 0, stream>>>(edge_src, edge_dst, edge_rel,
                                                           map, bin_ofs, s_src, s_mid, E);
  k_agg<<<8 * NBPR, 512, 0, stream>>>(X, W_rel, s_src, s_mid, cnt_c, bin_start, Hacc);
  k_final<<<256, 512, 0, stream>>>(X, W_self, bvec, uniq, counter, Hacc);
  k_score<<<(B * 64 + 255) / 256, 256, 0, stream>>>(Hacc, map, rel_emb, tri_nodes,
                                                    tri_rel, (float*)d_out, B);
}

// Round 5
// 243.484 us; speedup vs baseline: 12.4174x; 3.7753x over previous
//
#include <hip/hip_runtime.h>

// ---------------- build node -> compact id map ----------------
__global__ void k_build_map(const int* __restrict__ tri_nodes, int* __restrict__ map,
                            int* __restrict__ uniq, int* __restrict__ counter, int n) {
  int i = blockIdx.x * blockDim.x + threadIdx.x;
  if (i >= n) return;
  int node = tri_nodes[i];
  int old = atomicCAS(&map[node], -1, -2);
  if (old == -1) {
    int mid = atomicAdd(counter, 1);
    uniq[mid] = node;
    map[node] = mid;
  }
}

// ---------------- count needed edges per comb = mid*8+rel ----------------
__global__ void k_count(const int* __restrict__ edst, const int* __restrict__ erel,
                        const int* __restrict__ map, int* __restrict__ cnt_c, int E) {
  int stride = gridDim.x * blockDim.x;
  for (int i = blockIdx.x * blockDim.x + threadIdx.x; i < E; i += stride) {
    int mid = map[edst[i]];
    if (mid >= 0) atomicAdd(&cnt_c[mid * 8 + erel[i]], 1);
  }
}

// ---------------- hierarchical exclusive scan over M=262144 entries ----------------
// s1: 256 blocks x 256 thr x 4 entries -> block sums
__global__ __launch_bounds__(256) void k_scan_s1(const int* __restrict__ cnt_c,
                                                 int* __restrict__ bsum) {
  __shared__ int sh[256];
  int tid = threadIdx.x;
  int base = blockIdx.x * 1024 + tid * 4;
  int s = cnt_c[base] + cnt_c[base + 1] + cnt_c[base + 2] + cnt_c[base + 3];
  sh[tid] = s;
  __syncthreads();
  for (int o = 1; o < 256; o <<= 1) {
    int x = (tid >= o) ? sh[tid - o] : 0;
    __syncthreads();
    sh[tid] += x;
    __syncthreads();
  }
  if (tid == 255) bsum[blockIdx.x] = sh[255];
}
// s2: scan the 256 block sums in place (exclusive), write grand total to seg_start[M]
__global__ __launch_bounds__(256) void k_scan_s2(int* __restrict__ bsum,
                                                 int* __restrict__ seg_start, int M) {
  __shared__ int sh[256];
  int tid = threadIdx.x;
  int v = bsum[tid];
  sh[tid] = v;
  __syncthreads();
  for (int o = 1; o < 256; o <<= 1) {
    int x = (tid >= o) ? sh[tid - o] : 0;
    __syncthreads();
    sh[tid] += x;
    __syncthreads();
  }
  bsum[tid] = sh[tid] - v;  // exclusive
  if (tid == 255) seg_start[M] = sh[255];
}
// s3: redo local scan with block offset, write seg_start and seg_ofs
__global__ __launch_bounds__(256) void k_scan_s3(const int* __restrict__ cnt_c,
                                                 const int* __restrict__ bsum,
                                                 int* __restrict__ seg_start,
                                                 int* __restrict__ seg_ofs) {
  __shared__ int sh[256];
  int tid = threadIdx.x;
  int base = blockIdx.x * 1024 + tid * 4;
  int c0 = cnt_c[base], c1 = cnt_c[base + 1], c2 = cnt_c[base + 2], c3 = cnt_c[base + 3];
  int s = c0 + c1 + c2 + c3;
  sh[tid] = s;
  __syncthreads();
  for (int o = 1; o < 256; o <<= 1) {
    int x = (tid >= o) ? sh[tid - o] : 0;
    __syncthreads();
    sh[tid] += x;
    __syncthreads();
  }
  int run = bsum[blockIdx.x] + sh[tid] - s;
  seg_start[base] = run; seg_ofs[base] = run; run += c0;
  seg_start[base + 1] = run; seg_ofs[base + 1] = run; run += c1;
  seg_start[base + 2] = run; seg_ofs[base + 2] = run; run += c2;
  seg_start[base + 3] = run; seg_ofs[base + 3] = run;
}

// ---------------- scatter needed edge srcs into comb-sorted order ----------------
__global__ void k_scatter(const int* __restrict__ esrc, const int* __restrict__ edst,
                          const int* __restrict__ erel, const int* __restrict__ map,
                          int* __restrict__ seg_ofs, int* __restrict__ s_src, int E) {
  int stride = gridDim.x * blockDim.x;
  for (int i = blockIdx.x * blockDim.x + threadIdx.x; i < E; i += stride) {
    int mid = map[edst[i]];
    if (mid >= 0) {
      int comb = mid * 8 + erel[i];
      int pos = atomicAdd(&seg_ofs[comb], 1);
      s_src[pos] = esrc[i];
    }
  }
}

// ---------------- fused atomic-free RGCN GEMM ----------------
// One block per 128 mids. K-steps r=0..7: A-row = norm-scaled segment-sum of X rows
// (built in LDS by gather), B = W_rel[r]. Step r=8: A-row = X[uniq[mid]], B = W_self.
// Epilogue: +bias, relu, plain float4 store to Hacc. Zero atomics.
__global__ __launch_bounds__(512) void k_fused(
    const float* __restrict__ X, const float* __restrict__ W_rel,
    const float* __restrict__ W_self, const float* __restrict__ bvec,
    const int* __restrict__ uniq, const int* __restrict__ counter,
    const int* __restrict__ seg_start, const int* __restrict__ s_src,
    float* __restrict__ Hacc) {
  __shared__ float w_lds[128 * 128];   // 64 KB
  __shared__ float x_lds[128 * 132];   // 67.6 KB, XOR-swizzled float4s

  int nm = *counter;  // uniform
  int mid0 = blockIdx.x * 128;
  if (mid0 >= nm) return;  // fully-empty tile (rows never read)

  int t = threadIdx.x;
  int ty = t >> 5, tx = t & 31;   // compute micro-tile: rows ty*8..+7, cols tx*4..+3
  int er = t >> 2, qtr = t & 3;   // staging: row er, d-quarter qtr*32..+31

  float4 accum[8];
#pragma unroll
  for (int i = 0; i < 8; ++i) accum[i] = make_float4(0.f, 0.f, 0.f, 0.f);

  for (int r = 0; r < 9; ++r) {
    __syncthreads();  // previous compute done before overwriting LDS

    {  // stage B (W_rel[r] or W_self): 4096 float4 / 512 threads
      const float4* w4 = (const float4*)((r < 8) ? (W_rel + r * 16384) : W_self);
      float4* wl4 = (float4*)w_lds;
#pragma unroll
      for (int i = 0; i < 8; ++i) wl4[t + i * 512] = w4[t + i * 512];
    }

    {  // stage A row er quarter qtr: segment gather-reduce (or self row)
      float4 xa[8];
#pragma unroll
      for (int q = 0; q < 8; ++q) xa[q] = make_float4(0.f, 0.f, 0.f, 0.f);
      int mid = mid0 + er;
      if (r < 8) {
        int comb = mid * 8 + r;
        int s0 = seg_start[comb], s1 = seg_start[comb + 1];
        for (int e = s0; e < s1; ++e) {
          int src = s_src[e];
          const float4* xr = (const float4*)(X + (long long)src * 128) + qtr * 8;
#pragma unroll
          for (int q = 0; q < 8; ++q) {
            float4 v = xr[q];
            xa[q].x += v.x; xa[q].y += v.y; xa[q].z += v.z; xa[q].w += v.w;
          }
        }
        int n = s1 - s0;
        if (n > 1) {
          float sc = 1.0f / (float)n;
#pragma unroll
          for (int q = 0; q < 8; ++q) {
            xa[q].x *= sc; xa[q].y *= sc; xa[q].z *= sc; xa[q].w *= sc;
          }
        }
      } else if (mid < nm) {
        int node = uniq[mid];
        const float4* xr = (const float4*)(X + (long long)node * 128) + qtr * 8;
#pragma unroll
        for (int q = 0; q < 8; ++q) xa[q] = xr[q];
      }
      float4* xl4 = (float4*)(x_lds + er * 132);
      int key = (er >> 3) & 3;
#pragma unroll
      for (int q = 0; q < 8; ++q) xl4[(qtr * 8 + q) ^ key] = xa[q];
    }
    __syncthreads();

    // 128x128x128 tile GEMM step, 8x4 outputs/thread
    for (int d = 0; d < 128; d += 4) {
      int sw = d >> 2;
      float4 a[8];
#pragma unroll
      for (int i = 0; i < 8; ++i)
        a[i] = ((const float4*)(x_lds + (ty * 8 + i) * 132))[sw ^ (ty & 3)];
#pragma unroll
      for (int dd = 0; dd < 4; ++dd) {
        float4 b = *(const float4*)&w_lds[(d + dd) * 128 + tx * 4];
#pragma unroll
        for (int i = 0; i < 8; ++i) {
          float av = (dd == 0) ? a[i].x : (dd == 1) ? a[i].y : (dd == 2) ? a[i].z : a[i].w;
          accum[i].x += av * b.x;
          accum[i].y += av * b.y;
          accum[i].z += av * b.z;
          accum[i].w += av * b.w;
        }
      }
    }
  }

  // epilogue: bias + relu, plain stores
  float4 b4 = ((const float4*)bvec)[tx];
#pragma unroll
  for (int i = 0; i < 8; ++i) {
    int row = mid0 + ty * 8 + i;
    float4 v;
    v.x = accum[i].x + b4.x; v.y = accum[i].y + b4.y;
    v.z = accum[i].z + b4.z; v.w = accum[i].w + b4.w;
    v.x = v.x > 0.f ? v.x : 0.f;
    v.y = v.y > 0.f ? v.y : 0.f;
    v.z = v.z > 0.f ? v.z : 0.f;
    v.w = v.w > 0.f ? v.w : 0.f;
    *(float4*)(Hacc + (size_t)row * 128 + tx * 4) = v;
  }
}

// ---------------- DistMult score: one wave per triple ----------------
__global__ void k_score(const float* __restrict__ H, const int* __restrict__ map,
                        const float* __restrict__ rel_emb, const int* __restrict__ tri_nodes,
                        const int* __restrict__ tri_rel, float* __restrict__ out, int B) {
  int w = (blockIdx.x * blockDim.x + threadIdx.x) >> 6;
  int lane = threadIdx.x & 63;
  if (w >= B) return;
  int s = map[tri_nodes[w * 2]];
  int o = map[tri_nodes[w * 2 + 1]];
  const float* hs = H + (size_t)s * 128;
  const float* ho = H + (size_t)o * 128;
  const float* rr = rel_emb + (size_t)tri_rel[w] * 128;
  float p = hs[lane] * ho[lane] * rr[lane] + hs[lane + 64] * ho[lane + 64] * rr[lane + 64];
#pragma unroll
  for (int ofs = 32; ofs > 0; ofs >>= 1) p += __shfl_down(p, ofs);
  if (lane == 0) out[w] = p;
}

extern "C" void kernel_launch(void* const* d_in, const int* in_sizes, int n_in,
                              void* d_out, int out_size, void* d_ws, size_t ws_size,
                              hipStream_t stream) {
  const float* X       = (const float*)d_in[0];
  const float* W_rel   = (const float*)d_in[1];
  const float* W_self  = (const float*)d_in[2];
  const float* bvec    = (const float*)d_in[3];
  const float* rel_emb = (const float*)d_in[4];
  const int* edge_src  = (const int*)d_in[5];
  const int* edge_dst  = (const int*)d_in[6];
  const int* edge_rel  = (const int*)d_in[7];
  const int* tri_nodes = (const int*)d_in[8];
  const int* tri_rel   = (const int*)d_in[9];

  int N  = in_sizes[0] / 128;   // 100000
  int E  = in_sizes[5];         // 1600000
  int nt = in_sizes[8];         // 2*B = 32768 (max distinct needed nodes)
  int B  = in_sizes[9];         // 16384
  int M  = nt * 8;              // 262144 combs

  char* ws = (char*)d_ws;
  int* map       = (int*)ws;                 // N
  int* counter   = map + N;                  // 1 (+pad to 64)
  int* uniq      = counter + 64;             // nt
  int* cnt_c     = uniq + nt;                // M
  int* seg_start = cnt_c + M;                // M+1
  int* seg_ofs   = seg_start + M + 64;       // M
  int* bsum      = seg_ofs + M;              // 256
  int* s_src     = bsum + 256;               // E
  float* Hacc    = (float*)(s_src + E);      // nt*128 floats
  // total ws use: ~27 MB

  hipMemsetAsync(map, 0xFF, (size_t)N * 4, stream);      // -1
  hipMemsetAsync(counter, 0, 64 * 4, stream);
  hipMemsetAsync(cnt_c, 0, (size_t)M * 4, stream);

  k_build_map<<<(nt + 255) / 256, 256, 0, stream>>>(tri_nodes, map, uniq, counter, nt);
  k_count<<<1024, 256, 0, stream>>>(edge_dst, edge_rel, map, cnt_c, E);
  k_scan_s1<<<256, 256, 0, stream>>>(cnt_c, bsum);
  k_scan_s2<<<1, 256, 0, stream>>>(bsum, seg_start, M);
  k_scan_s3<<<256, 256, 0, stream>>>(cnt_c, bsum, seg_start, seg_ofs);
  k_scatter<<<1024, 256, 0, stream>>>(edge_src, edge_dst, edge_rel, map, seg_ofs,
                                      s_src, E);
  k_fused<<<nt / 128, 512, 0, stream>>>(X, W_rel, W_self, bvec, uniq, counter,
                                        seg_start, s_src, Hacc);
  k_score<<<(B * 64 + 255) / 256, 256, 0, stream>>>(Hacc, map, rel_emb, tri_nodes,
                                                    tri_rel, (float*)d_out, B);
}

// Round 7
// 146.313 us; speedup vs baseline: 20.6641x; 1.6641x over previous
//
#include <hip/hip_runtime.h>

typedef float f32x4 __attribute__((ext_vector_type(4)));
typedef short bf16x8 __attribute__((ext_vector_type(8)));

__device__ __forceinline__ unsigned short f2bf(float f) {
  unsigned int u = __float_as_uint(f);
  u += 0x7FFFu + ((u >> 16) & 1u);  // RNE
  return (unsigned short)(u >> 16);
}

// ---------------- build node -> compact id map ----------------
__global__ void k_build_map(const int* __restrict__ tri_nodes, int* __restrict__ map,
                            int* __restrict__ uniq, int* __restrict__ counter, int n) {
  int i = blockIdx.x * blockDim.x + threadIdx.x;
  if (i >= n) return;
  int node = tri_nodes[i];
  int old = atomicCAS(&map[node], -1, -2);
  if (old == -1) {
    int mid = atomicAdd(counter, 1);
    uniq[mid] = node;
    map[node] = mid;
  }
}

// ---------------- count needed edges per comb = mid*8+rel ----------------
__global__ void k_count(const int* __restrict__ edst, const int* __restrict__ erel,
                        const int* __restrict__ map, int* __restrict__ cnt_c, int E) {
  int stride = gridDim.x * blockDim.x;
  for (int i = blockIdx.x * blockDim.x + threadIdx.x; i < E; i += stride) {
    int mid = map[edst[i]];
    if (mid >= 0) atomicAdd(&cnt_c[mid * 8 + erel[i]], 1);
  }
}

// ---------------- hierarchical exclusive scan over M=262144 entries ----------------
__global__ __launch_bounds__(256) void k_scan_s1(const int* __restrict__ cnt_c,
                                                 int* __restrict__ bsum) {
  __shared__ int sh[256];
  int tid = threadIdx.x;
  int base = blockIdx.x * 1024 + tid * 4;
  int s = cnt_c[base] + cnt_c[base + 1] + cnt_c[base + 2] + cnt_c[base + 3];
  sh[tid] = s;
  __syncthreads();
  for (int o = 1; o < 256; o <<= 1) {
    int x = (tid >= o) ? sh[tid - o] : 0;
    __syncthreads();
    sh[tid] += x;
    __syncthreads();
  }
  if (tid == 255) bsum[blockIdx.x] = sh[255];
}
__global__ __launch_bounds__(256) void k_scan_s2(int* __restrict__ bsum,
                                                 int* __restrict__ seg_start, int M) {
  __shared__ int sh[256];
  int tid = threadIdx.x;
  int v = bsum[tid];
  sh[tid] = v;
  __syncthreads();
  for (int o = 1; o < 256; o <<= 1) {
    int x = (tid >= o) ? sh[tid - o] : 0;
    __syncthreads();
    sh[tid] += x;
    __syncthreads();
  }
  bsum[tid] = sh[tid] - v;  // exclusive
  if (tid == 255) seg_start[M] = sh[255];
}
__global__ __launch_bounds__(256) void k_scan_s3(const int* __restrict__ cnt_c,
                                                 const int* __restrict__ bsum,
                                                 int* __restrict__ seg_start,
                                                 int* __restrict__ seg_ofs) {
  __shared__ int sh[256];
  int tid = threadIdx.x;
  int base = blockIdx.x * 1024 + tid * 4;
  int c0 = cnt_c[base], c1 = cnt_c[base + 1], c2 = cnt_c[base + 2], c3 = cnt_c[base + 3];
  int s = c0 + c1 + c2 + c3;
  sh[tid] = s;
  __syncthreads();
  for (int o = 1; o < 256; o <<= 1) {
    int x = (tid >= o) ? sh[tid - o] : 0;
    __syncthreads();
    sh[tid] += x;
    __syncthreads();
  }
  int run = bsum[blockIdx.x] + sh[tid] - s;
  seg_start[base] = run; seg_ofs[base] = run; run += c0;
  seg_start[base + 1] = run; seg_ofs[base + 1] = run; run += c1;
  seg_start[base + 2] = run; seg_ofs[base + 2] = run; run += c2;
  seg_start[base + 3] = run; seg_ofs[base + 3] = run;
}

// ---------------- scatter needed edge srcs into comb-sorted order ----------------
__global__ void k_scatter(const int* __restrict__ esrc, const int* __restrict__ edst,
                          const int* __restrict__ erel, const int* __restrict__ map,
                          int* __restrict__ seg_ofs, int* __restrict__ s_src, int E) {
  int stride = gridDim.x * blockDim.x;
  for (int i = blockIdx.x * blockDim.x + threadIdx.x; i < E; i += stride) {
    int mid = map[edst[i]];
    if (mid >= 0) {
      int comb = mid * 8 + erel[i];
      int pos = atomicAdd(&seg_ofs[comb], 1);
      s_src[pos] = esrc[i];
    }
  }
}

// ---------------- W -> bf16 transposed [r][col=e][k=d] ----------------
// NOTE: Wt aliases the cnt_c region (dead after k_scan_s3) so the total ws
// footprint stays at round-5's proven high-water mark.
__global__ void k_cvt_w(const float* __restrict__ W_rel, const float* __restrict__ W_self,
                        unsigned short* __restrict__ Wt) {
  int i = blockIdx.x * 256 + threadIdx.x;  // over 9*16384
  if (i >= 9 * 16384) return;
  int r = i >> 14, rem = i & 16383;
  int e = rem >> 7, d = rem & 127;
  float v = (r < 8) ? W_rel[r * 16384 + d * 128 + e] : W_self[d * 128 + e];
  Wt[i] = f2bf(v);
}

// ---------------- fused RGCN GEMM on matrix cores ----------------
// 64-mid tile, 512 threads (8 waves, 2x4 wave grid, 32x32 sub-tile/wave).
// K-steps r=0..7: A-row = norm-scaled segment-sum of X rows (fp32 gather ->
// bf16 LDS), B = Wt[r]. r=8: self row + W_self. Epilogue: bias+relu, plain
// stores. 48 KB LDS.
__global__ __launch_bounds__(512) void k_fused(
    const float* __restrict__ X, const unsigned short* __restrict__ Wt,
    const float* __restrict__ bvec, const int* __restrict__ uniq,
    const int* __restrict__ counter, const int* __restrict__ seg_start,
    const int* __restrict__ s_src, float* __restrict__ Hacc) {
  __shared__ __align__(16) unsigned short a_lds[64 * 128];   // [row][k], 16B-unit XOR-swizzled
  __shared__ __align__(16) unsigned short w_lds[128 * 128];  // [col][k], swizzled

  int nm = *counter;
  int mid0 = blockIdx.x * 64;
  if (mid0 >= nm) return;

  int t = threadIdx.x;
  int er = t >> 3, oct = t & 7;                 // staging: row er, 16-elem chunk oct
  int lane = t & 63, l15 = lane & 15, lg = lane >> 4;
  int wid = t >> 6, wr = wid >> 2, wc = wid & 3;  // wave sub-tile (32 rows x 32 cols)
  int mid = mid0 + er;

  f32x4 acc[2][2];
#pragma unroll
  for (int m = 0; m < 2; ++m)
#pragma unroll
    for (int n = 0; n < 2; ++n) {
      f32x4 z = {0.f, 0.f, 0.f, 0.f};
      acc[m][n] = z;
    }

  for (int r = 0; r < 9; ++r) {
    __syncthreads();  // previous compute done before overwriting LDS

    {  // stage W tile: Wt[r] (2048 uint4) -> w_lds, swizzle unit ^ (col&7)
      const uint4* wg = (const uint4*)(Wt + r * 16384);
#pragma unroll
      for (int i = 0; i < 4; ++i) {
        int v = t + i * 512;
        int u = v ^ ((v >> 4) & 7);
        *(uint4*)&w_lds[u * 8] = wg[v];
      }
    }

    {  // stage A row er chunk oct: segment gather-reduce fp32 -> bf16
      float aa[16];
#pragma unroll
      for (int q = 0; q < 16; ++q) aa[q] = 0.f;
      if (r < 8) {
        int comb = mid * 8 + r;
        int s0 = seg_start[comb], s1 = seg_start[comb + 1];
        for (int e = s0; e < s1; ++e) {
          const float4* xr = (const float4*)(X + (size_t)s_src[e] * 128) + oct * 4;
#pragma unroll
          for (int q = 0; q < 4; ++q) {
            float4 v = xr[q];
            aa[q * 4 + 0] += v.x; aa[q * 4 + 1] += v.y;
            aa[q * 4 + 2] += v.z; aa[q * 4 + 3] += v.w;
          }
        }
        int cnt = s1 - s0;
        if (cnt > 1) {
          float sc = 1.0f / (float)cnt;
#pragma unroll
          for (int q = 0; q < 16; ++q) aa[q] *= sc;
        }
      } else if (mid < nm) {
        const float4* xr = (const float4*)(X + (size_t)uniq[mid] * 128) + oct * 4;
#pragma unroll
        for (int q = 0; q < 4; ++q) {
          float4 v = xr[q];
          aa[q * 4 + 0] = v.x; aa[q * 4 + 1] = v.y;
          aa[q * 4 + 2] = v.z; aa[q * 4 + 3] = v.w;
        }
      }
      unsigned int p[8];
#pragma unroll
      for (int q = 0; q < 8; ++q)
        p[q] = (unsigned int)f2bf(aa[q * 2]) | ((unsigned int)f2bf(aa[q * 2 + 1]) << 16);
      int unit0 = er * 16 + oct * 2, sw = er & 7;
      uint4 p0 = make_uint4(p[0], p[1], p[2], p[3]);
      uint4 p1 = make_uint4(p[4], p[5], p[6], p[7]);
      *(uint4*)&a_lds[((unit0) ^ sw) * 8] = p0;
      *(uint4*)&a_lds[((unit0 + 1) ^ sw) * 8] = p1;
    }
    __syncthreads();

    // ---- MFMA: 4 k-blocks x (2 row-frags x 2 col-frags)
#pragma unroll
    for (int kb = 0; kb < 4; ++kb) {
      int ku = kb * 4 + lg;  // 16B unit index along k for this lane group
      bf16x8 af[2], bfr[2];
#pragma unroll
      for (int m = 0; m < 2; ++m) {
        int row = wr * 32 + m * 16 + l15;
        af[m] = *(const bf16x8*)&a_lds[((row * 16 + ku) ^ (row & 7)) * 8];
      }
#pragma unroll
      for (int n = 0; n < 2; ++n) {
        int col = wc * 32 + n * 16 + l15;
        bfr[n] = *(const bf16x8*)&w_lds[((col * 16 + ku) ^ (col & 7)) * 8];
      }
#pragma unroll
      for (int m = 0; m < 2; ++m)
#pragma unroll
        for (int n = 0; n < 2; ++n)
          acc[m][n] = __builtin_amdgcn_mfma_f32_16x16x32_bf16(af[m], bfr[n], acc[m][n], 0, 0, 0);
    }
  }

  // epilogue: bias + relu, plain stores. C/D map: col=lane&15, row=(lane>>4)*4+reg
#pragma unroll
  for (int m = 0; m < 2; ++m) {
#pragma unroll
    for (int n = 0; n < 2; ++n) {
      int col = wc * 32 + n * 16 + l15;
      float bv = bvec[col];
#pragma unroll
      for (int q = 0; q < 4; ++q) {
        int row = mid0 + wr * 32 + m * 16 + lg * 4 + q;
        float v = acc[m][n][q] + bv;
        Hacc[(size_t)row * 128 + col] = v > 0.f ? v : 0.f;
      }
    }
  }
}

// ---------------- DistMult score: one wave per triple ----------------
__global__ void k_score(const float* __restrict__ H, const int* __restrict__ map,
                        const float* __restrict__ rel_emb, const int* __restrict__ tri_nodes,
                        const int* __restrict__ tri_rel, float* __restrict__ out, int B) {
  int w = (blockIdx.x * blockDim.x + threadIdx.x) >> 6;
  int lane = threadIdx.x & 63;
  if (w >= B) return;
  int s = map[tri_nodes[w * 2]];
  int o = map[tri_nodes[w * 2 + 1]];
  const float* hs = H + (size_t)s * 128;
  const float* ho = H + (size_t)o * 128;
  const float* rr = rel_emb + (size_t)tri_rel[w] * 128;
  float p = hs[lane] * ho[lane] * rr[lane] + hs[lane + 64] * ho[lane + 64] * rr[lane + 64];
#pragma unroll
  for (int ofs = 32; ofs > 0; ofs >>= 1) p += __shfl_down(p, ofs);
  if (lane == 0) out[w] = p;
}

extern "C" void kernel_launch(void* const* d_in, const int* in_sizes, int n_in,
                              void* d_out, int out_size, void* d_ws, size_t ws_size,
                              hipStream_t stream) {
  const float* X       = (const float*)d_in[0];
  const float* W_rel   = (const float*)d_in[1];
  const float* W_self  = (const float*)d_in[2];
  const float* bvec    = (const float*)d_in[3];
  const float* rel_emb = (const float*)d_in[4];
  const int* edge_src  = (const int*)d_in[5];
  const int* edge_dst  = (const int*)d_in[6];
  const int* edge_rel  = (const int*)d_in[7];
  const int* tri_nodes = (const int*)d_in[8];
  const int* tri_rel   = (const int*)d_in[9];

  int N  = in_sizes[0] / 128;   // 100000
  int E  = in_sizes[5];         // 1600000
  int nt = in_sizes[8];         // 2*B = 32768
  int B  = in_sizes[9];         // 16384
  int M  = nt * 8;              // 262144 combs

  char* ws = (char*)d_ws;
  int* map       = (int*)ws;                 // N
  int* counter   = map + N;                  // 1 (+pad 64)
  int* uniq      = counter + 64;             // nt
  int* cnt_c     = uniq + nt;                // M  (reused as Wt after scan_s3)
  int* seg_start = cnt_c + M;                // M+1 (+pad 64)
  int* seg_ofs   = seg_start + M + 64;       // M
  int* bsum      = seg_ofs + M;              // 256
  int* s_src     = bsum + 256;               // E
  float* Hacc    = (float*)(s_src + E);      // nt*128 floats
  unsigned short* Wt = (unsigned short*)cnt_c;  // 9*16384 bf16, aliases cnt_c (295KB < 1MB)
  // total ws use: ~26.9 MB (identical footprint to the round-5 version that
  // passed post-timing validation)

  hipMemsetAsync(map, 0xFF, (size_t)N * 4, stream);  // -1
  hipMemsetAsync(counter, 0, 64 * 4, stream);
  hipMemsetAsync(cnt_c, 0, (size_t)M * 4, stream);

  k_build_map<<<(nt + 255) / 256, 256, 0, stream>>>(tri_nodes, map, uniq, counter, nt);
  k_count<<<1024, 256, 0, stream>>>(edge_dst, edge_rel, map, cnt_c, E);
  k_scan_s1<<<256, 256, 0, stream>>>(cnt_c, bsum);
  k_scan_s2<<<1, 256, 0, stream>>>(bsum, seg_start, M);
  k_scan_s3<<<256, 256, 0, stream>>>(cnt_c, bsum, seg_start, seg_ofs);
  // cnt_c is dead from here on; overwrite it with the bf16 weights
  k_cvt_w<<<(9 * 16384 + 255) / 256, 256, 0, stream>>>(W_rel, W_self, Wt);
  k_scatter<<<1024, 256, 0, stream>>>(edge_src, edge_dst, edge_rel, map, seg_ofs,
                                      s_src, E);
  k_fused<<<nt / 64, 512, 0, stream>>>(X, Wt, bvec, uniq, counter, seg_start, s_src, Hacc);
  k_score<<<(B * 64 + 255) / 256, 256, 0, stream>>>(Hacc, map, rel_emb, tri_nodes,
                                                    tri_rel, (float*)d_out, B);
}